// Round 1
// 415.692 us; speedup vs baseline: 1.4579x; 1.4579x over previous
//
#include <hip/hip_runtime.h>
#include <cstddef>
#include <cstdint>

// ---------------- problem constants ----------------
#define HW    512
#define CCH   16
// conv tile: 16x16 output pixels per block, 18x18 halo
#define HTILE 18
#define NPIX  324          // 18*18
#define NSLOT 12           // uint4 slots per pixel (96 f16 = 8 cins x 12 kv)

typedef _Float16 f16x8 __attribute__((ext_vector_type(8)));
typedef float    f32x4 __attribute__((ext_vector_type(4)));

__device__ __forceinline__ float h2f(ushort u) {
    _Float16 h = __builtin_bit_cast(_Float16, u);
    return (float)h;
}
__device__ __forceinline__ ushort f2h(float f) {
    _Float16 h = (_Float16)f;
    return __builtin_bit_cast(ushort, h);
}
__device__ __forceinline__ uint pack2h(float a, float b) {
    return (uint)f2h(a) | ((uint)f2h(b) << 16);
}

// ---------------------------------------------------------------------------
// Derived values for one input x, packed as 12 f16 in 6 u32:
//   halves [0..10] = cubic B-spline bases 0..10 on uniform grid
//                    g(i) = -1.75 + 0.25*i   (kv = 0..10)
//   half  [11]     = silu(x)                 (kv = 11)
// Closed form: only 4 bases are nonzero (cell ci = floor(4x+7), local u),
// standard uniform cubic blending weights, placed via 64-bit funnel shift.
// ---------------------------------------------------------------------------
__device__ __forceinline__ void derived12(float x, uint* u) {
    float si = x / (1.0f + __expf(-x));          // silu
    float t  = fmaf(x, 4.0f, 7.0f);              // (x + 1.75) / 0.25
    t = fminf(fmaxf(t, -1.0f), 15.0f);           // keep ci in [-1,15]
    float ft = floorf(t);
    int   ci = (int)ft;
    float uu = t - ft;
    float um = 1.0f - uu;
    float u2 = uu * uu, m2 = um * um;
    float u3 = u2 * uu, m3 = m2 * um;
    const float c16 = 0.16666667f, c23 = 0.66666667f;
    float w0 = u3 * c16;                          // basis at i = ci     (j=0)
    float w3 = m3 * c16;                          // basis at i = ci - 3 (j=3)
    float w2 = fmaf(0.5f, u3, c23 - u2);          // j=2
    float w1 = fmaf(0.5f, m3, c23 - m2);          // j=1
    // P = [w3, w2, w1, w0] as 4 f16, lowest half first (increasing basis idx)
    uint64_t P = (uint64_t)f2h(w3)
               | ((uint64_t)f2h(w2) << 16)
               | ((uint64_t)f2h(w1) << 32)
               | ((uint64_t)f2h(w0) << 48);
    // place P at half-offset (ci - 3) within the 12-half output field
    int s = 16 * ci - 48;                         // bit offset, multiple of 16
    int d = s >> 6;                               // word index of P start (-1..2)
    int e = s & 63;
    uint64_t Q = P << e;
    uint64_t R = (P >> (63 - e)) >> 1;            // e==0 -> 0, else P >> (64-e)
    uint64_t O0 = (d == 0) ? Q : (d == -1) ? R : 0ull;
    uint64_t O1 = (d == 1) ? Q : (d ==  0) ? R : 0ull;
    uint64_t O2 = (d == 2) ? Q : (d ==  1) ? R : 0ull;
    // half 11 is silu; also clips basis spill for ci >= 11
    O2 = (O2 & 0x0000ffffffffffffull) | ((uint64_t)f2h(si) << 48);
    u[0] = (uint)O0; u[1] = (uint)(O0 >> 32);
    u[2] = (uint)O1; u[3] = (uint)(O1 >> 32);
    u[4] = (uint)O2; u[5] = (uint)(O2 >> 32);
}

// ---------------------------------------------------------------------------
// Weight prep: fp32 (bw, sw) -> f16 MFMA A-operand fragment tables.
// Logical K (per layer): chunk(2) x [ tap(9)*96 + cin'(8)*12 + kv(12) ],
// 54 steps of 32. kv = 0..10 -> spline basis kv, kv = 11 -> base (silu) weight.
// Fragment element j of lane l at step s = W[cout=l&15][k=32s+8q+j].
// ---------------------------------------------------------------------------
__global__ void __launch_bounds__(64) prep_w(
    const float* __restrict__ bw1, const float* __restrict__ sw1,
    const float* __restrict__ bw2, const float* __restrict__ sw2,
    uint4* __restrict__ wtab1, uint4* __restrict__ wtab2)
{
    const int s    = blockIdx.x;        // 0..53
    const int lane = threadIdx.x;       // 0..63
    const float* bw; const float* sw; uint4* wt;
    if (blockIdx.y == 0) { bw = bw1; sw = sw1; wt = wtab1; }
    else                 { bw = bw2; sw = sw2; wt = wtab2; }
    const int co = lane & 15, q = lane >> 4;
    const int chunk = s / 27, sl = s - chunk * 27;
    uint u[4];
#pragma unroll
    for (int jj = 0; jj < 4; ++jj) {
        float w[2];
#pragma unroll
        for (int h = 0; h < 2; ++h) {
            int j   = jj * 2 + h;
            int kl  = 32 * sl + 8 * q + j;     // k within chunk, 0..863
            int tap = kl / 96;
            int r   = kl - tap * 96;           // cin'*12 + kv
            int ci  = r / 12;
            int kv  = r - ci * 12;
            int cin = chunk * 8 + ci;
            w[h] = (kv == 11) ? bw[(co * 16 + cin) * 9 + tap]
                              : sw[(co * 176 + cin * 11 + kv) * 9 + tap];
        }
        u[jj] = pack2h(w[0], w[1]);
    }
    wt[s * 64 + lane] = make_uint4(u[0], u[1], u[2], u[3]);
}

// ---------------------------------------------------------------------------
// Fused KAN conv layer via f16 MFMA implicit GEMM.
// LDS layout is SLOT-MAJOR: dt16[slot][pixel], slot = 16B sub-word (0..11) of
// a pixel's 96 derived halves. MFMA-loop reads are 16 consecutive uint4 per
// 16-lane group (conflict-free) and share one vaddr with imm offsets.
// ---------------------------------------------------------------------------
template<bool IN_H, bool OUT_H>
__global__ __launch_bounds__(256, 2) void conv_mfma(
    const void* __restrict__ in_v,
    const uint4* __restrict__ wtab,
    void* __restrict__ out_v)
{
    __shared__ uint4 dt16[NSLOT * NPIX];   // 62208 B

    const int tid  = threadIdx.x;
    const int lane = tid & 63;
    const int wv   = tid >> 6;            // wave 0..3
    const int m    = lane & 15;           // pixel-x within tile (B/D "n" index)
    const int q    = lane >> 4;           // k-octet selector
    const int bx0  = blockIdx.x * 16;
    const int by0  = blockIdx.y * 16;
    const int b    = blockIdx.z;

    const float*  inf = (const float*)in_v;
    const ushort* inh = (const ushort*)in_v;

    f32x4 acc[4];
#pragma unroll
    for (int t = 0; t < 4; ++t) acc[t] = f32x4{0.f, 0.f, 0.f, 0.f};

#pragma unroll 1
    for (int chunk = 0; chunk < 2; ++chunk) {
        __syncthreads();   // previous chunk's reads complete before overwrite

        // ---- stage derived f16 tile: items = cp(4) x pix(324) ----
        {
            float v0[6], v1[6];
            uint  bofs[6];
            bool  live[6];
            // phase 1: issue all global loads (12 in flight) before any math
#pragma unroll
            for (int k = 0; k < 6; ++k) {
                int it  = tid + k * 256;
                bool lv = (it < NPIX * 4);
                int cp  = it / NPIX;           // 0..3 (consec lanes -> consec pix)
                int pix = it - cp * NPIX;
                int py  = pix / 18;
                int px  = pix - py * 18;
                int gy  = by0 + py - 1;
                int gx  = bx0 + px - 1;
                bool ok = lv && ((unsigned)gy < (unsigned)HW)
                             && ((unsigned)gx < (unsigned)HW);
                live[k] = lv;
                bofs[k] = (uint)(cp * 3 * NPIX + pix);
                float a = -1.0e9f, c = -1.0e9f;   // pad: silu->-0, bases->0
                if (ok) {
                    size_t base = ((size_t)(b * CCH + chunk * 8 + cp * 2) << 18)
                                + ((size_t)gy << 9) + gx;
                    if (IN_H) { a = h2f(inh[base]); c = h2f(inh[base + (1u << 18)]); }
                    else      { a = inf[base];      c = inf[base + (1u << 18)]; }
                }
                v0[k] = a; v1[k] = c;
            }
            // phase 2: derive + LDS write
#pragma unroll
            for (int k = 0; k < 6; ++k) {
                if (live[k]) {
                    uint uA[6], uB[6];
                    derived12(v0[k], uA);      // cin = 2cp
                    derived12(v1[k], uB);      // cin = 2cp+1
                    uint bo = bofs[k];
                    dt16[bo]            = make_uint4(uA[0], uA[1], uA[2], uA[3]);
                    dt16[bo + NPIX]     = make_uint4(uA[4], uA[5], uB[0], uB[1]);
                    dt16[bo + 2 * NPIX] = make_uint4(uB[2], uB[3], uB[4], uB[5]);
                }
            }
        }
        __syncthreads();

        // ---- register-resident weight frags for this chunk ----
        uint4 wf[27];
#pragma unroll
        for (int s = 0; s < 27; ++s) wf[s] = wtab[(chunk * 27 + s) * 64 + lane];

        // ---- K loop: 27 steps x 4 pixel-row tiles ----
        // read addr (uint4 units): (4*(s%3)+q)*NPIX + (wv*4+t+tdy)*18 + tdx + m
        const uint rbase = (uint)(q * NPIX + wv * 72 + m);
#pragma unroll
        for (int s = 0; s < 27; ++s) {
            const int tap = s / 3;
            const int tdy = tap / 3, tdx = tap - tdy * 3;
            const int j   = s - tap * 3;
#pragma unroll
            for (int t = 0; t < 4; ++t) {
                uint off = rbase + (uint)(j * (4 * NPIX) + (t + tdy) * HTILE + tdx);
                f16x8 a = *reinterpret_cast<const f16x8*>(&dt16[off]);
                acc[t] = __builtin_amdgcn_mfma_f32_16x16x32_f16(
                    __builtin_bit_cast(f16x8, wf[s]), a, acc[t], 0, 0, 0);
            }
        }
    }

    // ---- store: lane l reg r -> cout = 4q+r, px = m, row = wv*4+t ----
#pragma unroll
    for (int t = 0; t < 4; ++t) {
        int oy = by0 + wv * 4 + t;
#pragma unroll
        for (int r = 0; r < 4; ++r) {
            int co = q * 4 + r;
            size_t idx = ((size_t)(b * CCH + co) << 18) + ((size_t)oy << 9) + (bx0 + m);
            if (OUT_H) ((ushort*)out_v)[idx] = f2h(acc[t][r]);
            else       ((float*)out_v)[idx]  = acc[t][r];
        }
    }
}

// ---------------- instance-norm reductions ----------------
__global__ void __launch_bounds__(256) reduce_partial_h(
    const ushort* __restrict__ zh, float* __restrict__ part)
{
    const int bc = blockIdx.y;
    const uint* p = (const uint*)(zh + ((size_t)bc << 18) + ((size_t)blockIdx.x << 12));
    float s = 0.0f, qq = 0.0f;
    for (int i = threadIdx.x; i < 2048; i += 256) {
        uint u = p[i];
        float a = h2f((ushort)(u & 0xffffu));
        float c = h2f((ushort)(u >> 16));
        s += a + c;
        qq = fmaf(a, a, qq);
        qq = fmaf(c, c, qq);
    }
#pragma unroll
    for (int off = 32; off > 0; off >>= 1) {
        s  += __shfl_down(s, off);
        qq += __shfl_down(qq, off);
    }
    __shared__ float ls[4], lq[4];
    const int wid = threadIdx.x >> 6;
    if ((threadIdx.x & 63) == 0) { ls[wid] = s; lq[wid] = qq; }
    __syncthreads();
    if (threadIdx.x == 0) {
        part[((size_t)bc * 64 + blockIdx.x) * 2]     = ls[0] + ls[1] + ls[2] + ls[3];
        part[((size_t)bc * 64 + blockIdx.x) * 2 + 1] = lq[0] + lq[1] + lq[2] + lq[3];
    }
}

__global__ void __launch_bounds__(256) reduce_partial(
    const float* __restrict__ z, float* __restrict__ part)
{
    const int bc = blockIdx.y;
    const float* p = z + ((size_t)bc << 18) + ((size_t)blockIdx.x << 12);
    float s = 0.0f, qq = 0.0f;
    for (int i = threadIdx.x; i < 4096; i += 256) {
        float v = p[i];
        s += v;
        qq = fmaf(v, v, qq);
    }
#pragma unroll
    for (int off = 32; off > 0; off >>= 1) {
        s  += __shfl_down(s, off);
        qq += __shfl_down(qq, off);
    }
    __shared__ float ls[4], lq[4];
    const int wid = threadIdx.x >> 6;
    if ((threadIdx.x & 63) == 0) { ls[wid] = s; lq[wid] = qq; }
    __syncthreads();
    if (threadIdx.x == 0) {
        part[((size_t)bc * 64 + blockIdx.x) * 2]     = ls[0] + ls[1] + ls[2] + ls[3];
        part[((size_t)bc * 64 + blockIdx.x) * 2 + 1] = lq[0] + lq[1] + lq[2] + lq[3];
    }
}

__global__ void __launch_bounds__(256) reduce_final(
    const float* __restrict__ part, float* __restrict__ stats)
{
    const int tid = threadIdx.x;       // 256 = 64 bc x 4 lanes
    const int bc  = tid >> 2;
    const int j   = tid & 3;
    float s = 0.0f, qq = 0.0f;
    for (int i = j; i < 64; i += 4) {
        s  += part[((size_t)bc * 64 + i) * 2];
        qq += part[((size_t)bc * 64 + i) * 2 + 1];
    }
    s  += __shfl_down(s, 1);  s  += __shfl_down(s, 2);
    qq += __shfl_down(qq, 1); qq += __shfl_down(qq, 2);
    if (j == 0) {
        const float inv = 1.0f / 262144.0f;
        float mval = s * inv;
        float var  = qq * inv - mval * mval;
        stats[bc * 2]     = mval;
        stats[bc * 2 + 1] = rsqrtf(var + 1e-5f);
    }
}

// y = prelu(instancenorm(z)) in place on f16 buffer; 1 uint2 (4 halves)/thread.
__global__ void __launch_bounds__(256) norm_prelu_h(
    ushort* __restrict__ y, const float* __restrict__ stats,
    const float* __restrict__ a_ptr)
{
    const float a = *a_ptr;
    const int i2 = blockIdx.x * 256 + threadIdx.x;   // 4194304 uint2 units
    const int bc = i2 >> 16;                         // 65536 units per bc
    const float mm = stats[bc * 2];
    const float rr = stats[bc * 2 + 1];
    uint2* py = (uint2*)y;
    uint2 v = py[i2];
    float f0 = h2f((ushort)(v.x & 0xffffu)), f1 = h2f((ushort)(v.x >> 16));
    float f2 = h2f((ushort)(v.y & 0xffffu)), f3 = h2f((ushort)(v.y >> 16));
    f0 = (f0 - mm) * rr; f0 = (f0 >= 0.f) ? f0 : a * f0;
    f1 = (f1 - mm) * rr; f1 = (f1 >= 0.f) ? f1 : a * f1;
    f2 = (f2 - mm) * rr; f2 = (f2 >= 0.f) ? f2 : a * f2;
    f3 = (f3 - mm) * rr; f3 = (f3 >= 0.f) ? f3 : a * f3;
    v.x = pack2h(f0, f1);
    v.y = pack2h(f2, f3);
    py[i2] = v;
}

// out = sigmoid(prelu(instancenorm(z2))) in place on d_out, float4-wide.
__global__ void __launch_bounds__(256) final_sigmoid(
    float* __restrict__ out, const float* __restrict__ stats,
    const float* __restrict__ a_ptr)
{
    const float a = *a_ptr;
    const int i4 = blockIdx.x * 256 + threadIdx.x;
    const int bc = i4 >> 16;
    const float mm = stats[bc * 2];
    const float rr = stats[bc * 2 + 1];
    float4 v = reinterpret_cast<float4*>(out)[i4];
    float t;
    t = (v.x - mm) * rr; t = (t >= 0.f) ? t : a * t; v.x = 1.0f / (1.0f + __expf(-t));
    t = (v.y - mm) * rr; t = (t >= 0.f) ? t : a * t; v.y = 1.0f / (1.0f + __expf(-t));
    t = (v.z - mm) * rr; t = (t >= 0.f) ? t : a * t; v.z = 1.0f / (1.0f + __expf(-t));
    t = (v.w - mm) * rr; t = (t >= 0.f) ? t : a * t; v.w = 1.0f / (1.0f + __expf(-t));
    reinterpret_cast<float4*>(out)[i4] = v;
}

extern "C" void kernel_launch(void* const* d_in, const int* in_sizes, int n_in,
                              void* d_out, int out_size, void* d_ws, size_t ws_size,
                              hipStream_t stream)
{
    const float* x        = (const float*)d_in[0];
    const float* base_w1  = (const float*)d_in[1];
    const float* spline_w1= (const float*)d_in[2];
    const float* prelu_a1 = (const float*)d_in[3];
    const float* base_w2  = (const float*)d_in[4];
    const float* spline_w2= (const float*)d_in[5];
    const float* prelu_a2 = (const float*)d_in[6];
    float* out_f = (float*)d_out;
    char*  wsb   = (char*)d_ws;

    // ws layout (all within 64 MiB):
    //   z1h    @ 0          : 4*16*512*512*2 = 33554432 B (f16, reused as y1h)
    //   wtab1  @ 33554432   : 54*64*16 = 55296 B
    //   wtab2  @ 33609728   : 55296 B
    //   part   @ 33665024   : 64*64*2*4 = 32768 B
    //   stats1 @ 33697792   : 512 B
    //   stats2 @ 33698304   : 512 B
    ushort* z1h    = (ushort*)wsb;
    uint4*  wtab1  = (uint4*)(wsb + 33554432);
    uint4*  wtab2  = (uint4*)(wsb + 33609728);
    float*  part   = (float*)(wsb + 33665024);
    float*  stats1 = (float*)(wsb + 33697792);
    float*  stats2 = (float*)(wsb + 33698304);

    dim3 cgrid(HW / 16, HW / 16, 4);   // (32,32,4)
    dim3 cblk(256);
    dim3 rgrid(64, 64);

    // weight tables for both layers
    prep_w<<<dim3(54, 2), 64, 0, stream>>>(base_w1, spline_w1, base_w2, spline_w2,
                                           wtab1, wtab2);

    // ---- layer 1: x (fp32) -> z1 (f16) ----
    conv_mfma<false, true><<<cgrid, cblk, 0, stream>>>(x, wtab1, z1h);
    reduce_partial_h<<<rgrid, cblk, 0, stream>>>(z1h, part);
    reduce_final<<<1, 256, 0, stream>>>(part, stats1);
    norm_prelu_h<<<16384, cblk, 0, stream>>>(z1h, stats1, prelu_a1);  // z1h -> y1h

    // ---- layer 2: y1 (f16) -> z2 (fp32, d_out) ----
    conv_mfma<true, false><<<cgrid, cblk, 0, stream>>>(z1h, wtab2, out_f);
    reduce_partial<<<rgrid, cblk, 0, stream>>>(out_f, part);
    reduce_final<<<1, 256, 0, stream>>>(part, stats2);

    // ---- final: norm + prelu + sigmoid in place on d_out ----
    final_sigmoid<<<16384, cblk, 0, stream>>>(out_f, stats2, prelu_a2);
}

// Round 4
// 356.000 us; speedup vs baseline: 1.7023x; 1.1677x over previous
//
#include <hip/hip_runtime.h>
#include <cstddef>
#include <cstdint>

// ---------------- problem constants ----------------
#define HW    512
#define CCH   16
// conv tile: 16x16 output pixels per block, 18x18 halo
#define HTILE 18
#define NPIX  324          // 18*18
#define NSLOT 12           // uint4 slots per pixel (96 f16 = 8 cins x 12 kv)

typedef _Float16 f16x8 __attribute__((ext_vector_type(8)));
typedef float    f32x4 __attribute__((ext_vector_type(4)));

__device__ __forceinline__ float h2f(ushort u) {
    _Float16 h = __builtin_bit_cast(_Float16, u);
    return (float)h;
}
__device__ __forceinline__ ushort f2h(float f) {
    _Float16 h = (_Float16)f;
    return __builtin_bit_cast(ushort, h);
}
__device__ __forceinline__ uint pack2h(float a, float b) {
    return (uint)f2h(a) | ((uint)f2h(b) << 16);
}

// ---------------------------------------------------------------------------
// Derived values for one input x, packed as 12 f16 in 6 u32:
//   halves [0..10] = cubic B-spline bases 0..10 on uniform grid
//                    g(i) = -1.75 + 0.25*i   (kv = 0..10)
//   half  [11]     = silu(x)                 (kv = 11)
// Closed form: only 4 bases are nonzero (cell ci = floor(4x+7), local u),
// standard uniform cubic blending weights, placed via 64-bit funnel shift.
// ---------------------------------------------------------------------------
__device__ __forceinline__ void derived12(float x, uint* u) {
    float si = x / (1.0f + __expf(-x));          // silu
    float t  = fmaf(x, 4.0f, 7.0f);              // (x + 1.75) / 0.25
    t = fminf(fmaxf(t, -1.0f), 15.0f);           // keep ci in [-1,15]
    float ft = floorf(t);
    int   ci = (int)ft;
    float uu = t - ft;
    float um = 1.0f - uu;
    float u2 = uu * uu, m2 = um * um;
    float u3 = u2 * uu, m3 = m2 * um;
    const float c16 = 0.16666667f, c23 = 0.66666667f;
    float w0 = u3 * c16;                          // basis at i = ci     (j=0)
    float w3 = m3 * c16;                          // basis at i = ci - 3 (j=3)
    float w2 = fmaf(0.5f, u3, c23 - u2);          // j=2
    float w1 = fmaf(0.5f, m3, c23 - m2);          // j=1
    // P = [w3, w2, w1, w0] as 4 f16, lowest half first (increasing basis idx)
    uint64_t P = (uint64_t)f2h(w3)
               | ((uint64_t)f2h(w2) << 16)
               | ((uint64_t)f2h(w1) << 32)
               | ((uint64_t)f2h(w0) << 48);
    // place P at half-offset (ci - 3) within the 12-half output field
    int s = 16 * ci - 48;                         // bit offset, multiple of 16
    int d = s >> 6;                               // word index of P start (-1..2)
    int e = s & 63;
    uint64_t Q = P << e;
    uint64_t R = (P >> (63 - e)) >> 1;            // e==0 -> 0, else P >> (64-e)
    uint64_t O0 = (d == 0) ? Q : (d == -1) ? R : 0ull;
    uint64_t O1 = (d == 1) ? Q : (d ==  0) ? R : 0ull;
    uint64_t O2 = (d == 2) ? Q : (d ==  1) ? R : 0ull;
    // half 11 is silu; also clips basis spill for ci >= 11
    O2 = (O2 & 0x0000ffffffffffffull) | ((uint64_t)f2h(si) << 48);
    u[0] = (uint)O0; u[1] = (uint)(O0 >> 32);
    u[2] = (uint)O1; u[3] = (uint)(O1 >> 32);
    u[4] = (uint)O2; u[5] = (uint)(O2 >> 32);
}

// ---------------------------------------------------------------------------
// Weight prep: fp32 (bw, sw) -> f16 MFMA A-operand fragment tables.
// Logical K (per layer): chunk(2) x [ tap(9)*96 + cin'(8)*12 + kv(12) ],
// 54 steps of 32. kv = 0..10 -> spline basis kv, kv = 11 -> base (silu) weight.
// Fragment element j of lane l at step s = W[cout=l&15][k=32s+8q+j].
// Also zeroes the per-layer stats accumulation buffers (fresh every launch).
// ---------------------------------------------------------------------------
__global__ void __launch_bounds__(64) prep_w(
    const float* __restrict__ bw1, const float* __restrict__ sw1,
    const float* __restrict__ bw2, const float* __restrict__ sw2,
    uint4* __restrict__ wtab1, uint4* __restrict__ wtab2,
    float* __restrict__ part1, float* __restrict__ part2)
{
    const int s    = blockIdx.x;        // 0..53
    const int lane = threadIdx.x;       // 0..63
    const float* bw; const float* sw; uint4* wt;
    if (blockIdx.y == 0) { bw = bw1; sw = sw1; wt = wtab1; }
    else                 { bw = bw2; sw = sw2; wt = wtab2; }

    if (s == 0) {   // zero the stats accumulators (128 floats each)
        float* p = (blockIdx.y == 0) ? part1 : part2;
        p[lane] = 0.0f;
        p[64 + lane] = 0.0f;
    }

    const int co = lane & 15, q = lane >> 4;
    const int chunk = s / 27, sl = s - chunk * 27;
    uint u[4];
#pragma unroll
    for (int jj = 0; jj < 4; ++jj) {
        float w[2];
#pragma unroll
        for (int h = 0; h < 2; ++h) {
            int j   = jj * 2 + h;
            int kl  = 32 * sl + 8 * q + j;     // k within chunk, 0..863
            int tap = kl / 96;
            int r   = kl - tap * 96;           // cin'*12 + kv
            int ci  = r / 12;
            int kv  = r - ci * 12;
            int cin = chunk * 8 + ci;
            w[h] = (kv == 11) ? bw[(co * 16 + cin) * 9 + tap]
                              : sw[(co * 176 + cin * 11 + kv) * 9 + tap];
        }
        u[jj] = pack2h(w[0], w[1]);
    }
    wt[s * 64 + lane] = make_uint4(u[0], u[1], u[2], u[3]);
}

// ---------------------------------------------------------------------------
// Fused KAN conv layer via f16 MFMA implicit GEMM.
// LDS layout is SLOT-MAJOR: dt16[slot][pixel], slot = 16B sub-word (0..11) of
// a pixel's 96 derived halves.
// NORM_IN: apply instance-norm + prelu (from stats_in/a_in) to the input
// values during staging (fuses the inter-layer elementwise pass).
// Epilogue: per-block (sum, sumsq) per cout -> atomicAdd into part_out
// (fuses the instance-norm partial reduction of this layer's output).
// K loop uses row-register reuse: for each (j, tdx), 6 ds_read_b128 feed
// 12 MFMAs (was 12 reads) -> halves LDS read traffic.
// ---------------------------------------------------------------------------
template<bool IN_H, bool OUT_H, bool NORM_IN>
__global__ __launch_bounds__(256, 2) void conv_mfma(
    const void* __restrict__ in_v,
    const uint4* __restrict__ wtab,
    void* __restrict__ out_v,
    const float* __restrict__ stats_in,
    const float* __restrict__ a_in,
    float* __restrict__ part_out)
{
    __shared__ uint4 dt16[NSLOT * NPIX];   // 62208 B
    __shared__ float sn[32];               // [cin][{mean, rstd}] for NORM_IN

    const int tid  = threadIdx.x;
    const int lane = tid & 63;
    const int wv   = tid >> 6;            // wave 0..3
    const int m    = lane & 15;           // pixel-x within tile (B/D "n" index)
    const int q    = lane >> 4;           // k-octet selector
    const int bx0  = blockIdx.x * 16;
    const int by0  = blockIdx.y * 16;
    const int b    = blockIdx.z;

    const float*  inf = (const float*)in_v;
    const ushort* inh = (const ushort*)in_v;

    float pa = 0.0f;
    if (NORM_IN) {
        pa = *a_in;
        if (tid < 32) sn[tid] = stats_in[b * 32 + tid];
        // first __syncthreads below orders this vs. use
    }

    f32x4 acc[4];
#pragma unroll
    for (int t = 0; t < 4; ++t) acc[t] = f32x4{0.f, 0.f, 0.f, 0.f};

#pragma unroll 1
    for (int chunk = 0; chunk < 2; ++chunk) {
        __syncthreads();   // previous chunk's reads complete before overwrite

        // ---- stage derived f16 tile: items = cp(4) x pix(324) ----
        float v0[6], v1[6];
        uint  bofs[6], cps[6];
        bool  live[6];
        // phase 1: issue all global loads (12 in flight) before any math
#pragma unroll
        for (int k = 0; k < 6; ++k) {
            int it  = tid + k * 256;
            bool lv = (it < NPIX * 4);
            int cp  = it / NPIX;           // 0..3 (consec lanes -> consec pix)
            int pix = it - cp * NPIX;
            int py  = pix / 18;
            int px  = pix - py * 18;
            int gy  = by0 + py - 1;
            int gx  = bx0 + px - 1;
            bool ok = lv && ((unsigned)gy < (unsigned)HW)
                         && ((unsigned)gx < (unsigned)HW);
            live[k] = lv;
            cps[k]  = (uint)cp;
            bofs[k] = (uint)(cp * 3 * NPIX + pix);
            float a = -1.0e9f, c = -1.0e9f;   // pad: silu->-0, bases->0
            if (ok) {
                size_t base = ((size_t)(b * CCH + chunk * 8 + cp * 2) << 18)
                            + ((size_t)gy << 9) + gx;
                if (IN_H) { a = h2f(inh[base]); c = h2f(inh[base + (1u << 18)]); }
                else      { a = inf[base];      c = inf[base + (1u << 18)]; }
            }
            v0[k] = a; v1[k] = c;
        }

        // ---- register-resident weight frags for this chunk (loads in
        //      flight while derived math runs) ----
        uint4 wf[27];
#pragma unroll
        for (int s = 0; s < 27; ++s) wf[s] = wtab[(chunk * 27 + s) * 64 + lane];

        // phase 2: (optional norm+prelu) + derive + LDS write
#pragma unroll
        for (int k = 0; k < 6; ++k) {
            if (live[k]) {
                float a0 = v0[k], c0 = v1[k];
                if (NORM_IN) {
                    int ci2 = (chunk * 8 + (int)cps[k] * 2) * 2;
                    a0 = (a0 - sn[ci2])     * sn[ci2 + 1];
                    a0 = (a0 >= 0.f) ? a0 : pa * a0;
                    c0 = (c0 - sn[ci2 + 2]) * sn[ci2 + 3];
                    c0 = (c0 >= 0.f) ? c0 : pa * c0;
                }
                uint uA[6], uB[6];
                derived12(a0, uA);      // cin = 2cp
                derived12(c0, uB);      // cin = 2cp+1
                uint bo = bofs[k];
                dt16[bo]            = make_uint4(uA[0], uA[1], uA[2], uA[3]);
                dt16[bo + NPIX]     = make_uint4(uA[4], uA[5], uB[0], uB[1]);
                dt16[bo + 2 * NPIX] = make_uint4(uB[2], uB[3], uB[4], uB[5]);
            }
        }
        __syncthreads();

        // ---- K loop: row-register reuse. addr (uint4 units):
        //      (4j+q)*NPIX + (wv*4 + t + tdy)*18 + (m + tdx) ----
        const uint pixbase = (uint)(wv * 72 + m);
#pragma unroll
        for (int j = 0; j < 3; ++j) {
            const uint slotoff = (uint)((j * 4 + q) * NPIX) + pixbase;
#pragma unroll
            for (int tdx = 0; tdx < 3; ++tdx) {
                f16x8 brow[6];
#pragma unroll
                for (int r6 = 0; r6 < 6; ++r6)
                    brow[r6] = *reinterpret_cast<const f16x8*>(
                        &dt16[slotoff + (uint)(r6 * HTILE + tdx)]);
#pragma unroll
                for (int tdy = 0; tdy < 3; ++tdy) {
                    const int s = (tdy * 3 + tdx) * 3 + j;
#pragma unroll
                    for (int t = 0; t < 4; ++t) {
                        acc[t] = __builtin_amdgcn_mfma_f32_16x16x32_f16(
                            __builtin_bit_cast(f16x8, wf[s]), brow[t + tdy],
                            acc[t], 0, 0, 0);
                    }
                }
            }
        }
    }

    // ---- store: lane l reg r -> cout = 4q+r, px = m, row = wv*4+t ----
#pragma unroll
    for (int t = 0; t < 4; ++t) {
        int oy = by0 + wv * 4 + t;
#pragma unroll
        for (int r = 0; r < 4; ++r) {
            int co = q * 4 + r;
            size_t idx = ((size_t)(b * CCH + co) << 18) + ((size_t)oy << 9) + (bx0 + m);
            if (OUT_H) ((ushort*)out_v)[idx] = f2h(acc[t][r]);
            else       ((float*)out_v)[idx]  = acc[t][r];
        }
    }

    // ---- fused instance-norm partial stats: per-(b,co) sum / sumsq ----
    float s4[4], q4[4];
#pragma unroll
    for (int r = 0; r < 4; ++r) {
        s4[r] = acc[0][r] + acc[1][r] + acc[2][r] + acc[3][r];
        q4[r] = fmaf(acc[0][r], acc[0][r],
                fmaf(acc[1][r], acc[1][r],
                fmaf(acc[2][r], acc[2][r], acc[3][r] * acc[3][r])));
    }
#pragma unroll
    for (int off = 8; off > 0; off >>= 1) {
#pragma unroll
        for (int r = 0; r < 4; ++r) {
            s4[r] += __shfl_xor(s4[r], off);
            q4[r] += __shfl_xor(q4[r], off);
        }
    }
    __syncthreads();                  // K-loop LDS reads done; reuse as scratch
    float* scr = (float*)dt16;        // [wv][co][{s,q}] = 128 floats
    if (m == 0) {
#pragma unroll
        for (int r = 0; r < 4; ++r) {
            scr[(wv * 16 + q * 4 + r) * 2 + 0] = s4[r];
            scr[(wv * 16 + q * 4 + r) * 2 + 1] = q4[r];
        }
    }
    __syncthreads();
    if (tid < 32) {
        int co = tid >> 1, which = tid & 1;
        float v = scr[(0 * 16 + co) * 2 + which] + scr[(1 * 16 + co) * 2 + which]
                + scr[(2 * 16 + co) * 2 + which] + scr[(3 * 16 + co) * 2 + which];
        atomicAdd(&part_out[(size_t)(b * CCH + co) * 2 + which], v);
    }
}

// ---- stats finalize: part (sum, sumsq over 262144) -> (mean, rstd) ----
__global__ void __launch_bounds__(64) reduce_final(
    const float* __restrict__ part, float* __restrict__ stats)
{
    const int bc = threadIdx.x;   // 0..63
    const float inv = 1.0f / 262144.0f;
    float s  = part[bc * 2];
    float qq = part[bc * 2 + 1];
    float mval = s * inv;
    float var  = qq * inv - mval * mval;
    stats[bc * 2]     = mval;
    stats[bc * 2 + 1] = rsqrtf(var + 1e-5f);
}

// out = sigmoid(prelu(instancenorm(z2))) in place on d_out, float4-wide.
__global__ void __launch_bounds__(256) final_sigmoid(
    float* __restrict__ out, const float* __restrict__ stats,
    const float* __restrict__ a_ptr)
{
    const float a = *a_ptr;
    const int i4 = blockIdx.x * 256 + threadIdx.x;
    const int bc = i4 >> 16;
    const float mm = stats[bc * 2];
    const float rr = stats[bc * 2 + 1];
    float4 v = reinterpret_cast<float4*>(out)[i4];
    float t;
    t = (v.x - mm) * rr; t = (t >= 0.f) ? t : a * t; v.x = 1.0f / (1.0f + __expf(-t));
    t = (v.y - mm) * rr; t = (t >= 0.f) ? t : a * t; v.y = 1.0f / (1.0f + __expf(-t));
    t = (v.z - mm) * rr; t = (t >= 0.f) ? t : a * t; v.z = 1.0f / (1.0f + __expf(-t));
    t = (v.w - mm) * rr; t = (t >= 0.f) ? t : a * t; v.w = 1.0f / (1.0f + __expf(-t));
    reinterpret_cast<float4*>(out)[i4] = v;
}

extern "C" void kernel_launch(void* const* d_in, const int* in_sizes, int n_in,
                              void* d_out, int out_size, void* d_ws, size_t ws_size,
                              hipStream_t stream)
{
    const float* x        = (const float*)d_in[0];
    const float* base_w1  = (const float*)d_in[1];
    const float* spline_w1= (const float*)d_in[2];
    const float* prelu_a1 = (const float*)d_in[3];
    const float* base_w2  = (const float*)d_in[4];
    const float* spline_w2= (const float*)d_in[5];
    const float* prelu_a2 = (const float*)d_in[6];
    float* out_f = (float*)d_out;
    char*  wsb   = (char*)d_ws;

    // ws layout (all within 64 MiB):
    //   z1h    @ 0          : 4*16*512*512*2 = 33554432 B (f16, raw conv1 out)
    //   wtab1  @ 33554432   : 54*64*16 = 55296 B
    //   wtab2  @ 33609728   : 55296 B
    //   part1  @ 33665024   : 128*4 = 512 B
    //   part2  @ 33665536   : 512 B
    //   stats1 @ 33666048   : 512 B
    //   stats2 @ 33666560   : 512 B
    ushort* z1h    = (ushort*)wsb;
    uint4*  wtab1  = (uint4*)(wsb + 33554432);
    uint4*  wtab2  = (uint4*)(wsb + 33609728);
    float*  part1  = (float*)(wsb + 33665024);
    float*  part2  = (float*)(wsb + 33665536);
    float*  stats1 = (float*)(wsb + 33666048);
    float*  stats2 = (float*)(wsb + 33666560);

    dim3 cgrid(HW / 16, HW / 16, 4);   // (32,32,4)
    dim3 cblk(256);

    // weight tables for both layers + zero stats accumulators
    prep_w<<<dim3(54, 2), 64, 0, stream>>>(base_w1, spline_w1, base_w2, spline_w2,
                                           wtab1, wtab2, part1, part2);

    // ---- layer 1: x (fp32) -> z1 (f16, raw) + partial stats ----
    conv_mfma<false, true, false><<<cgrid, cblk, 0, stream>>>(
        x, wtab1, z1h, nullptr, nullptr, part1);
    reduce_final<<<1, 64, 0, stream>>>(part1, stats1);

    // ---- layer 2: y1 = prelu(norm(z1)) fused into staging; -> z2 (fp32) ----
    conv_mfma<true, false, true><<<cgrid, cblk, 0, stream>>>(
        z1h, wtab2, out_f, stats1, prelu_a1, part2);
    reduce_final<<<1, 64, 0, stream>>>(part2, stats2);

    // ---- final: norm + prelu + sigmoid in place on d_out ----
    final_sigmoid<<<16384, cblk, 0, stream>>>(out_f, stats2, prelu_a2);
}